// Round 5
// baseline (475.599 us; speedup 1.0000x reference)
//
#include <hip/hip_runtime.h>

// Problem constants
constexpr int N_NODES = 50000;
constexpr int E_EDGES = 800000;
constexpr int CSR_CAP = E_EDGES + 4 * N_NODES;  // padded-to-4 capacity
constexpr int IN_DIM  = 128;
constexpr int HID     = 64;
constexpr int HEADS   = 4;
constexpr int HH      = HEADS * HID;            // 256
constexpr int EDGE_DIM = 8;
constexpr int L_LAYERS = 2;
constexpr float NEG_SLOPE = 0.2f;
constexpr int NB_SCAN = (N_NODES + 255) / 256;  // 196

typedef float floatx2 __attribute__((ext_vector_type(2)));

__device__ __forceinline__ unsigned short f2bf(float f) {
    unsigned int b = __float_as_uint(f);
    unsigned int r = (b + 0x7FFFu + ((b >> 16) & 1u)) >> 16;  // RNE
    return (unsigned short)r;
}
__device__ __forceinline__ float bf2f(unsigned short u) {
    return __uint_as_float(((unsigned int)u) << 16);
}
__device__ __forceinline__ float lrelu(float x) { return fmaxf(x, NEG_SLOPE * x); }

// fp8 e4m3 (OCP) pack/unpack via gfx950 HW converts
__device__ __forceinline__ unsigned char f2fp8(float v) {
    return (unsigned char)(__builtin_amdgcn_cvt_pk_fp8_f32(v, v, 0, false) & 0xFF);
}
__device__ __forceinline__ void fp8x4_to_f32(unsigned int w, float& a, float& b,
                                             float& c, float& d) {
    floatx2 lo = __builtin_amdgcn_cvt_pk_f32_fp8((int)w, false);
    floatx2 hi = __builtin_amdgcn_cvt_pk_f32_fp8((int)w, true);
    a = lo.x; b = lo.y; c = hi.x; d = hi.y;
}

// ---------------- x = x_in @ proj_w + proj_b -------------------------
__global__ void proj_kernel(const float* __restrict__ x, const float* __restrict__ w,
                            const float* __restrict__ b, float* __restrict__ out) {
    int base = blockIdx.x * 16;
    int c = threadIdx.x & 63;
    int g = threadIdx.x >> 6;  // 0..3
    __shared__ float xs[16][IN_DIM];
    for (int i = threadIdx.x; i < 16 * IN_DIM; i += 256) {
        int r = i >> 7, k = i & 127;
        xs[r][k] = x[(size_t)(base + r) * IN_DIM + k];
    }
    __syncthreads();
    float acc[4];
    float bc = b[c];
#pragma unroll
    for (int j = 0; j < 4; ++j) acc[j] = bc;
    for (int k0 = 0; k0 < IN_DIM; k0 += 4) {
        float w0 = w[(k0 + 0) * HID + c];
        float w1 = w[(k0 + 1) * HID + c];
        float w2 = w[(k0 + 2) * HID + c];
        float w3 = w[(k0 + 3) * HID + c];
#pragma unroll
        for (int j = 0; j < 4; ++j) {
            float4 xv = *(const float4*)&xs[g + 4 * j][k0];
            acc[j] += xv.x * w0 + xv.y * w1 + xv.z * w2 + xv.w * w3;
        }
    }
#pragma unroll
    for (int j = 0; j < 4; ++j) out[(size_t)(base + g + 4 * j) * HID + c] = acc[j];
}

// ---------------- edge-attr histogram --------------------------------
__global__ void count_attr_kernel(const int* __restrict__ attr, int* __restrict__ counts) {
    int c0 = 0, c1 = 0, c2 = 0;
    for (int i = blockIdx.x * blockDim.x + threadIdx.x; i < E_EDGES; i += gridDim.x * blockDim.x) {
        int a = attr[i];
        c0 += (a == 0); c1 += (a == 1); c2 += (a == 2);
    }
    for (int o = 32; o; o >>= 1) {
        c0 += __shfl_down(c0, o);
        c1 += __shfl_down(c1, o);
        c2 += __shfl_down(c2, o);
    }
    if ((threadIdx.x & 63) == 0) {
        atomicAdd(&counts[0], c0);
        atomicAdd(&counts[1], c1);
        atomicAdd(&counts[2], c2);
    }
}

// ---------------- eet[l][t][hc] for BOTH layers ----------------------
__global__ void eet2_kernel(const float* __restrict__ edge_emb, const float* __restrict__ We,
                            const int* __restrict__ counts, float* __restrict__ eet) {
    int hc = threadIdx.x;  // 256
    float inv = 1.f / (float)E_EDGES;
    for (int l = 0; l < L_LAYERS; ++l) {
        const float* We_l = We + (size_t)l * EDGE_DIM * HH;
        float* eet_l = eet + (size_t)l * 4 * HH;
        for (int t = 0; t < 3; ++t) {
            float acc = 0.f;
#pragma unroll
            for (int d = 0; d < EDGE_DIM; ++d) acc += edge_emb[t * EDGE_DIM + d] * We_l[d * HH + hc];
            eet_l[t * HH + hc] = acc;
        }
        float acc = 0.f;
#pragma unroll
        for (int d = 0; d < EDGE_DIM; ++d) {
            float md = (counts[0] * edge_emb[0 * EDGE_DIM + d] +
                        counts[1] * edge_emb[1 * EDGE_DIM + d] +
                        counts[2] * edge_emb[2 * EDGE_DIM + d]) * inv;
            acc += md * We_l[d * HH + hc];
        }
        eet_l[3 * HH + hc] = acc;
    }
}

// ---------------- CSR build ------------------------------------------
__global__ void hist_kernel(const int* __restrict__ dst, int* __restrict__ deg) {
    int e = blockIdx.x * 256 + threadIdx.x;
    if (e >= E_EDGES) return;
    atomicAdd(&deg[dst[e]], 1);
}

__global__ void scan1_kernel(const int* __restrict__ deg, int* __restrict__ loc,
                             int* __restrict__ sums) {
    __shared__ int s[256];
    int i = blockIdx.x * 256 + threadIdx.x;
    int v = (i < N_NODES) ? ((deg[i] + 4) & ~3) : 0;
    s[threadIdx.x] = v;
    __syncthreads();
    for (int o = 1; o < 256; o <<= 1) {
        int t = (threadIdx.x >= o) ? s[threadIdx.x - o] : 0;
        __syncthreads();
        s[threadIdx.x] += t;
        __syncthreads();
    }
    if (i < N_NODES) loc[i] = s[threadIdx.x] - v;
    if (threadIdx.x == 255) sums[blockIdx.x] = s[255];
}

__global__ void scan2_kernel(int* __restrict__ sums) {
    __shared__ int s[256];
    int v = (threadIdx.x < NB_SCAN) ? sums[threadIdx.x] : 0;
    s[threadIdx.x] = v;
    __syncthreads();
    for (int o = 1; o < 256; o <<= 1) {
        int t = (threadIdx.x >= o) ? s[threadIdx.x - o] : 0;
        __syncthreads();
        s[threadIdx.x] += t;
        __syncthreads();
    }
    if (threadIdx.x < NB_SCAN) sums[threadIdx.x] = s[threadIdx.x] - v;
}

__global__ void finalize_kernel(const int* __restrict__ loc, const int* __restrict__ sums,
                                const int* __restrict__ deg, int* __restrict__ offsets,
                                int* __restrict__ fill, unsigned int* __restrict__ csr) {
    int n = blockIdx.x * 256 + threadIdx.x;
    if (n >= N_NODES) return;
    int off = loc[n] + sums[n >> 8];
    offsets[n] = off;
    unsigned int selfe = (unsigned int)n | (3u << 16);  // type 3 = mean edge feat
    int cnt = deg[n] + 1;
    int pad = (cnt + 3) & ~3;
    csr[off] = selfe;
    for (int p = cnt; p < pad; ++p) csr[off + p] = selfe;  // masked dummies
    fill[n] = off + 1;
}

__global__ void scatter_kernel(const int* __restrict__ src, const int* __restrict__ dst,
                               const int* __restrict__ attr, int* __restrict__ fill,
                               unsigned int* __restrict__ csr) {
    int e = blockIdx.x * 256 + threadIdx.x;
    if (e >= E_EDGES) return;
    int d = dst[e];
    int pos = atomicAdd(&fill[d], 1);
    csr[pos] = (unsigned int)src[e] | ((unsigned int)attr[e] << 16);
}

// ---------------- xl = x@Wl (fp8 out), xr = x@Wr (bf16 out) ----------
__global__ void transform_kernel(const float* __restrict__ x, const float* __restrict__ Wl,
                                 const float* __restrict__ Wr, unsigned char* __restrict__ xl,
                                 unsigned short* __restrict__ xr) {
    int base = blockIdx.x * 16;
    int hc = threadIdx.x;  // 256
    __shared__ float xs[16][HID];
    for (int i = threadIdx.x; i < 16 * HID; i += 256) {
        int r = i >> 6, k = i & 63;
        xs[r][k] = x[(size_t)(base + r) * HID + k];
    }
    __syncthreads();
    float al[16], ar[16];
#pragma unroll
    for (int i = 0; i < 16; ++i) { al[i] = 0.f; ar[i] = 0.f; }
    for (int k0 = 0; k0 < HID; k0 += 4) {
        float wl0 = Wl[(k0 + 0) * HH + hc], wr0 = Wr[(k0 + 0) * HH + hc];
        float wl1 = Wl[(k0 + 1) * HH + hc], wr1 = Wr[(k0 + 1) * HH + hc];
        float wl2 = Wl[(k0 + 2) * HH + hc], wr2 = Wr[(k0 + 2) * HH + hc];
        float wl3 = Wl[(k0 + 3) * HH + hc], wr3 = Wr[(k0 + 3) * HH + hc];
#pragma unroll
        for (int i = 0; i < 16; ++i) {
            float4 xv = *(const float4*)&xs[i][k0];
            al[i] += xv.x * wl0 + xv.y * wl1 + xv.z * wl2 + xv.w * wl3;
            ar[i] += xv.x * wr0 + xv.y * wr1 + xv.z * wr2 + xv.w * wr3;
        }
    }
#pragma unroll
    for (int i = 0; i < 16; ++i) {
        xl[(size_t)(base + i) * HH + hc] = f2fp8(al[i]);
        xr[(size_t)(base + i) * HH + hc] = f2bf(ar[i]);
    }
}

// ---------------- Fused GAT: score + softmax + aggregate + LN --------
// One wave per dst node; 4 edges per iteration; xl gathered as fp8 (4 B/lane).
__global__ void gat_fused_kernel(const unsigned int* __restrict__ csr,
                                 const int* __restrict__ offsets, const int* __restrict__ deg,
                                 const unsigned char* __restrict__ xl,
                                 const unsigned short* __restrict__ xr,
                                 const float* __restrict__ eet_l, const float* __restrict__ att_l,
                                 const float* __restrict__ bias_l, const float* __restrict__ lnw,
                                 const float* __restrict__ lnb, const float* __restrict__ x_res,
                                 float* __restrict__ x_out) {
    __shared__ float4 eetS[256];  // [4 types][64 lanes]
    eetS[threadIdx.x] = ((const float4*)eet_l)[threadIdx.x];
    __syncthreads();
    int n = blockIdx.x * 4 + (threadIdx.x >> 6);
    int lane = threadIdx.x & 63;
    float4 av = *(const float4*)(att_l + lane * 4);
    ushort4 xrv = *(const ushort4*)(xr + (size_t)n * HH + lane * 4);
    float xr0 = bf2f(xrv.x), xr1 = bf2f(xrv.y), xr2 = bf2f(xrv.z), xr3 = bf2f(xrv.w);
    int beg = offsets[n];
    int cnt = deg[n] + 1;
    int rounds = (cnt + 3) >> 2;
    const unsigned char* xlb = xl + lane * 4;  // per-lane channel base (4 ch = 4 B)
    float accA0 = 0.f, accA1 = 0.f, accA2 = 0.f, accA3 = 0.f, denA = 0.f;
    float accB0 = 0.f, accB1 = 0.f, accB2 = 0.f, accB3 = 0.f, denB = 0.f;
    for (int it = 0; it < rounds; ++it) {
        uint4 ew = *(const uint4*)(csr + beg + (it << 2));
        int rem = cnt - (it << 2);  // #valid edges this round (>=1)
        int s0 = ew.x & 0xFFFFu, t0 = ew.x >> 16;
        int s1 = ew.y & 0xFFFFu, t1 = ew.y >> 16;
        int s2 = ew.z & 0xFFFFu, t2 = ew.z >> 16;
        int s3 = ew.w & 0xFFFFu, t3 = ew.w >> 16;
        unsigned int xw0 = *(const unsigned int*)(xlb + (size_t)s0 * HH);
        unsigned int xw1 = *(const unsigned int*)(xlb + (size_t)s1 * HH);
        unsigned int xw2 = *(const unsigned int*)(xlb + (size_t)s2 * HH);
        unsigned int xw3 = *(const unsigned int*)(xlb + (size_t)s3 * HH);
        float4 ee0 = eetS[(t0 << 6) + lane];
        float4 ee1 = eetS[(t1 << 6) + lane];
        float4 ee2 = eetS[(t2 << 6) + lane];
        float4 ee3 = eetS[(t3 << 6) + lane];
        float a0, a1, a2, a3, b0, b1, b2, b3, c0, c1, c2, c3, d0, d1, d2, d3;
        fp8x4_to_f32(xw0, a0, a1, a2, a3);
        fp8x4_to_f32(xw1, b0, b1, b2, b3);
        fp8x4_to_f32(xw2, c0, c1, c2, c3);
        fp8x4_to_f32(xw3, d0, d1, d2, d3);
        float p0 = lrelu(a0 + xr0 + ee0.x) * av.x + lrelu(a1 + xr1 + ee0.y) * av.y +
                   lrelu(a2 + xr2 + ee0.z) * av.z + lrelu(a3 + xr3 + ee0.w) * av.w;
        float p1 = lrelu(b0 + xr0 + ee1.x) * av.x + lrelu(b1 + xr1 + ee1.y) * av.y +
                   lrelu(b2 + xr2 + ee1.z) * av.z + lrelu(b3 + xr3 + ee1.w) * av.w;
        float p2 = lrelu(c0 + xr0 + ee2.x) * av.x + lrelu(c1 + xr1 + ee2.y) * av.y +
                   lrelu(c2 + xr2 + ee2.z) * av.z + lrelu(c3 + xr3 + ee2.w) * av.w;
        float p3 = lrelu(d0 + xr0 + ee3.x) * av.x + lrelu(d1 + xr1 + ee3.y) * av.y +
                   lrelu(d2 + xr2 + ee3.z) * av.z + lrelu(d3 + xr3 + ee3.w) * av.w;
        p0 += __shfl_xor(p0, 1); p1 += __shfl_xor(p1, 1);
        p2 += __shfl_xor(p2, 1); p3 += __shfl_xor(p3, 1);
        p0 += __shfl_xor(p0, 2); p1 += __shfl_xor(p1, 2);
        p2 += __shfl_xor(p2, 2); p3 += __shfl_xor(p3, 2);
        p0 += __shfl_xor(p0, 4); p1 += __shfl_xor(p1, 4);
        p2 += __shfl_xor(p2, 4); p3 += __shfl_xor(p3, 4);
        p0 += __shfl_xor(p0, 8); p1 += __shfl_xor(p1, 8);
        p2 += __shfl_xor(p2, 8); p3 += __shfl_xor(p3, 8);
        float w0 = __expf(p0);
        float w1 = (rem > 1) ? __expf(p1) : 0.f;
        float w2 = (rem > 2) ? __expf(p2) : 0.f;
        float w3 = (rem > 3) ? __expf(p3) : 0.f;
        denA += w0 + w1;
        denB += w2 + w3;
        accA0 += w0 * a0 + w1 * b0;  accB0 += w2 * c0 + w3 * d0;
        accA1 += w0 * a1 + w1 * b1;  accB1 += w2 * c1 + w3 * d1;
        accA2 += w0 * a2 + w1 * b2;  accB2 += w2 * c2 + w3 * d2;
        accA3 += w0 * a3 + w1 * b3;  accB3 += w2 * c3 + w3 * d3;
    }
    float inv = 1.f / (denA + denB);
    float r0 = (accA0 + accB0) * inv, r1 = (accA1 + accB1) * inv;
    float r2 = (accA2 + accB2) * inv, r3 = (accA3 + accB3) * inv;
    // sum across heads (lanes differing in bits 4,5)
    r0 += __shfl_xor(r0, 16); r1 += __shfl_xor(r1, 16);
    r2 += __shfl_xor(r2, 16); r3 += __shfl_xor(r3, 16);
    r0 += __shfl_xor(r0, 32); r1 += __shfl_xor(r1, 32);
    r2 += __shfl_xor(r2, 32); r3 += __shfl_xor(r3, 32);
    if (lane < 16) {
        float4 xc = *(const float4*)(x_res + (size_t)n * HID + lane * 4);
        float4 bb = *(const float4*)(bias_l + lane * 4);
        float h0 = 0.25f * r0 + bb.x + xc.x;
        float h1 = 0.25f * r1 + bb.y + xc.y;
        float h2 = 0.25f * r2 + bb.z + xc.z;
        float h3 = 0.25f * r3 + bb.w + xc.w;
        float sum = h0 + h1 + h2 + h3;
        sum += __shfl_xor(sum, 1); sum += __shfl_xor(sum, 2);
        sum += __shfl_xor(sum, 4); sum += __shfl_xor(sum, 8);
        float mu = sum * (1.f / 64.f);
        float d0_ = h0 - mu, d1_ = h1 - mu, d2_ = h2 - mu, d3_ = h3 - mu;
        float vs = d0_ * d0_ + d1_ * d1_ + d2_ * d2_ + d3_ * d3_;
        vs += __shfl_xor(vs, 1); vs += __shfl_xor(vs, 2);
        vs += __shfl_xor(vs, 4); vs += __shfl_xor(vs, 8);
        float rstd = rsqrtf(vs * (1.f / 64.f) + 1e-5f);
        float4 w4 = *(const float4*)(lnw + lane * 4);
        float4 b4 = *(const float4*)(lnb + lane * 4);
        float4 o;
        o.x = d0_ * rstd * w4.x + b4.x;
        o.y = d1_ * rstd * w4.y + b4.y;
        o.z = d2_ * rstd * w4.z + b4.z;
        o.w = d3_ * rstd * w4.w + b4.w;
        *(float4*)(x_out + (size_t)n * HID + lane * 4) = o;
    }
}

extern "C" void kernel_launch(void* const* d_in, const int* in_sizes, int n_in,
                              void* d_out, int out_size, void* d_ws, size_t ws_size,
                              hipStream_t stream) {
    const float* x_in     = (const float*)d_in[0];
    const int*   edge_idx = (const int*)d_in[1];
    const int*   attr     = (const int*)d_in[2];
    const float* proj_w   = (const float*)d_in[3];
    const float* proj_b   = (const float*)d_in[4];
    const float* edge_emb = (const float*)d_in[5];
    const float* Wl       = (const float*)d_in[6];
    const float* Wr       = (const float*)d_in[7];
    const float* We       = (const float*)d_in[8];
    const float* att      = (const float*)d_in[9];
    const float* bias     = (const float*)d_in[10];
    const float* ln_w     = (const float*)d_in[11];
    const float* ln_b     = (const float*)d_in[12];
    float* out = (float*)d_out;

    const int* src_idx = edge_idx;
    const int* dst_idx = edge_idx + E_EDGES;

    // Workspace layout
    float* ws = (float*)d_ws;
    float* x0 = ws;                                            // N*HID f32
    float* x1 = x0 + (size_t)N_NODES * HID;                    // N*HID f32
    unsigned char* xl_f8 = (unsigned char*)(x1 + (size_t)N_NODES * HID);   // N*HH u8
    unsigned short* xr_bf = (unsigned short*)(xl_f8 + (size_t)N_NODES * HH); // N*HH u16
    unsigned int* csr = (unsigned int*)(xr_bf + (size_t)N_NODES * HH);     // CSR_CAP
    int* offsets = (int*)(csr + CSR_CAP);                      // N
    int* deg     = offsets + N_NODES;                          // N
    int* fill    = deg + N_NODES;                              // N
    int* loc     = fill + N_NODES;                             // N
    int* sums    = loc + N_NODES;                              // 256
    float* eet   = (float*)(sums + 256);                       // L*4*HH
    int* counts  = (int*)(eet + L_LAYERS * 4 * HH);            // 4

    hipMemsetAsync(deg, 0, (size_t)N_NODES * sizeof(int), stream);
    hipMemsetAsync(counts, 0, 4 * sizeof(int), stream);

    proj_kernel<<<N_NODES / 16, 256, 0, stream>>>(x_in, proj_w, proj_b, x0);
    count_attr_kernel<<<256, 256, 0, stream>>>(attr, counts);

    // CSR build (once; graph is layer-invariant)
    hist_kernel<<<(E_EDGES + 255) / 256, 256, 0, stream>>>(dst_idx, deg);
    scan1_kernel<<<NB_SCAN, 256, 0, stream>>>(deg, loc, sums);
    scan2_kernel<<<1, 256, 0, stream>>>(sums);
    finalize_kernel<<<NB_SCAN, 256, 0, stream>>>(loc, sums, deg, offsets, fill, csr);
    scatter_kernel<<<(E_EDGES + 255) / 256, 256, 0, stream>>>(src_idx, dst_idx, attr, fill, csr);
    eet2_kernel<<<1, 256, 0, stream>>>(edge_emb, We, counts, eet);

    for (int l = 0; l < L_LAYERS; ++l) {
        const float* Wl_l = Wl + (size_t)l * HID * HH;
        const float* Wr_l = Wr + (size_t)l * HID * HH;
        const float* att_l = att + (size_t)l * HH;
        const float* bias_l = bias + (size_t)l * HID;
        const float* lnw_l = ln_w + (size_t)l * HID;
        const float* lnb_l = ln_b + (size_t)l * HID;
        const float* eet_l = eet + (size_t)l * 4 * HH;

        const float* x_cur = (l == 0) ? x0 : x1;
        float* x_next = (l == L_LAYERS - 1) ? out : x1;

        transform_kernel<<<N_NODES / 16, 256, 0, stream>>>(x_cur, Wl_l, Wr_l, xl_f8, xr_bf);
        gat_fused_kernel<<<N_NODES / 4, 256, 0, stream>>>(csr, offsets, deg, xl_f8, xr_bf, eet_l,
                                                          att_l, bias_l, lnw_l, lnb_l, x_cur, x_next);
    }
}